// Round 7
// baseline (557.284 us; speedup 1.0000x reference)
//
#include <hip/hip_runtime.h>

#define BB 8
#define CC 256
#define DD 128
#define NN 4096
#define BN_EPS 1e-5f

typedef _Float16 f16;
typedef _Float16 half8 __attribute__((ext_vector_type(8)));
typedef _Float16 half2t __attribute__((ext_vector_type(2)));
typedef float f32x4 __attribute__((ext_vector_type(4)));

__device__ __forceinline__ f32x4 mfma16(half8 a, half8 b, f32x4 c) {
  return __builtin_amdgcn_mfma_f32_16x16x32_f16(a, b, c, 0, 0, 0);
}

__device__ __forceinline__ half2t pkrtz(float a, float b) {
  auto t = __builtin_amdgcn_cvt_pkrtz(a, b);
  return __builtin_bit_cast(half2t, t);
}

#define EXP2(x) __builtin_amdgcn_exp2f(x)

// key permutation: swapped-QK register layout feeds PV A-fragment with zero data movement
#define PERM(i) ((((i) >> 5) & 1) * 32 + (((i) >> 2) & 3) * 8 + (((i) >> 4) & 1) * 4 + ((i) & 3))

// ---------- weights cast (fp32 -> fp16), stats zero ----------
__global__ void k_cast_weights(const float* __restrict__ tw, const float* __restrict__ pw,
                               const float* __restrict__ gw, const float* __restrict__ ww,
                               f16* __restrict__ Wcat, f16* __restrict__ Wwh,
                               float* __restrict__ stats) {
  int i = blockIdx.x * 256 + threadIdx.x;
  if (i < 32768) Wcat[i] = (f16)tw[i];
  else if (i < 65536) Wcat[i] = (f16)pw[i - 32768];
  else if (i < 98304) Wcat[i] = (f16)gw[i - 65536];
  else if (i < 131072) Wwh[i - 98304] = (f16)ww[i - 98304];
  if (i < 512) stats[i] = 0.f;
}

// ---------- x [B][C][N] f32 -> xT [B][N][C] f16 ----------
__global__ void k_transpose_x(const float* __restrict__ x, f16* __restrict__ xT) {
  __shared__ f16 tile[32][33];
  int b = blockIdx.z, c0 = blockIdx.y * 32, n0 = blockIdx.x * 32;
  int tx = threadIdx.x, ty = threadIdx.y;
  const float* xp = x + ((size_t)b * CC + c0) * NN + n0;
  for (int j = 0; j < 4; ++j) {
    int cc = ty + j * 8;
    tile[cc][tx] = (f16)xp[(size_t)cc * NN + tx];
  }
  __syncthreads();
  f16* xo = xT + ((size_t)b * NN + n0) * CC + c0;
  for (int j = 0; j < 4; ++j) {
    int nn = ty + j * 8;
    xo[(size_t)nn * CC + tx] = tile[tx][nn];
  }
}

// ---------- projections ----------
__global__ __launch_bounds__(256) void k_gemm1(const f16* __restrict__ xT, const f16* __restrict__ Wcat,
                                               f16* __restrict__ T, f16* __restrict__ P,
                                               f16* __restrict__ Gnd) {
  int b = blockIdx.z;
  int lane = threadIdx.x & 63, wave = threadIdx.x >> 6;
  int lr = lane & 15, lg = lane >> 4;
  int wr = wave >> 1, wc = wave & 1;
  int m0 = blockIdx.x * 64 + wr * 32;
  int c0 = blockIdx.y * 64 + wc * 32;
  const f16* A = xT + (size_t)b * NN * CC;
  f32x4 acc[2][2] = {};
  for (int k0 = 0; k0 < CC; k0 += 32) {
    half8 a[2], w[2];
    for (int i = 0; i < 2; ++i)
      a[i] = *(const half8*)(A + (size_t)(m0 + i * 16 + lr) * CC + k0 + lg * 8);
    for (int j = 0; j < 2; ++j)
      w[j] = *(const half8*)(Wcat + (size_t)(c0 + j * 16 + lr) * CC + k0 + lg * 8);
    for (int i = 0; i < 2; ++i)
      for (int j = 0; j < 2; ++j)
        acc[i][j] = mfma16(a[i], w[j], acc[i][j]);
  }
  for (int i = 0; i < 2; ++i)
    for (int j = 0; j < 2; ++j)
      for (int r = 0; r < 4; ++r) {
        int row = m0 + i * 16 + lg * 4 + r;
        int col = c0 + j * 16 + lr;
        f16 v = (f16)acc[i][j][r];
        size_t base = (size_t)b * NN + row;
        if (col < DD) T[base * DD + col] = v;
        else if (col < 2 * DD) P[base * DD + col - DD] = v;
        else Gnd[base * DD + col - 2 * DD] = v;
      }
}

// ---------- Gnd [B][N][D] -> Gdn [B][D][N] ----------
__global__ void k_transpose_g(const f16* __restrict__ Gnd, f16* __restrict__ Gdn) {
  __shared__ f16 tile[32][33];
  int b = blockIdx.z, d0 = blockIdx.y * 32, n0 = blockIdx.x * 32;
  int tx = threadIdx.x, ty = threadIdx.y;
  for (int j = 0; j < 4; ++j) {
    int nn = ty + j * 8;
    tile[nn][tx] = Gnd[((size_t)b * NN + n0 + nn) * DD + d0 + tx];
  }
  __syncthreads();
  for (int j = 0; j < 4; ++j) {
    int dd = ty + j * 8;
    Gdn[((size_t)b * DD + d0 + dd) * NN + n0 + tx] = tile[tx][dd];
  }
}

// ---------- flash attention: NO LDS, direct-from-L2 fragments, KV-split x2 ----------
// 1024 blocks (b = bid&7 pins batch->XCD; K+V = 2MB fits the 4MB XCD L2).
// 4 waves/block, 16 q/wave, 32 KV iters of 64 keys. Zero barriers: waves independent.
// Swapped QK (mfma(K,Q)), PERM'd K rows, l accumulated via mfma(af, ones).
// Outputs UNNORMALIZED f16 acc + per-q (m, l); k_merge combines the 2 halves.
__global__ __launch_bounds__(256) void k_flash(const f16* __restrict__ T, const f16* __restrict__ P,
                                               const f16* __restrict__ Gdn, f16* __restrict__ acc0,
                                               f16* __restrict__ acc1, float* __restrict__ ml) {
  int bid = blockIdx.x;
  int b = bid & 7;
  int u = bid >> 3;      // 0..127
  int half = u & 1;
  int qx = u >> 1;       // 0..63
  int lane = threadIdx.x & 63, wave = threadIdx.x >> 6;
  int lr = lane & 15, lg = lane >> 4;
  int q0 = qx * 64 + wave * 16;
  const f16* Tb = T + (size_t)b * NN * DD;
  const f16* Pb = P + (size_t)b * NN * DD;
  const f16* vpb = Gdn + (size_t)b * DD * NN + (size_t)lr * NN + lg * 8;
  int srcq = 4 * lg;

  const f16* kp[4];
  for (int kt = 0; kt < 4; ++kt)
    kp[kt] = Pb + (size_t)PERM(kt * 16 + lr) * DD + lg * 8;

  half8 qf[4];
  for (int ks = 0; ks < 4; ++ks) {
    half8 v = *(const half8*)(Tb + (size_t)(q0 + lr) * DD + ks * 32 + lg * 8);
    for (int j = 0; j < 8; ++j) v[j] *= (f16)1.44269504f;  // log2(e) into Q
    qf[ks] = v;
  }
  half8 ones;
  for (int j = 0; j < 8; ++j) ones[j] = (f16)1.f;

  f32x4 acc[8] = {};
  f32x4 lsum = {};
  float m_run = -1e30f;

  for (int kb = 0; kb < 32; ++kb) {
    int key0 = half * 2048 + kb * 64;
    // K fragments (16 loads, 64B/row segments; L1-shared across the block's waves)
    half8 kf[4][4];
    for (int kt = 0; kt < 4; ++kt)
      for (int ks = 0; ks < 4; ++ks)
        kf[kt][ks] = *(const half8*)(kp[kt] + (size_t)key0 * DD + ks * 32);
    // V fragments issued before QK consumes kf -> latency overlaps QK+softmax
    half8 vf[8][2];
    for (int nb = 0; nb < 8; ++nb)
      for (int kst = 0; kst < 2; ++kst)
        vf[nb][kst] = *(const half8*)(vpb + (size_t)nb * 16 * NN + key0 + kst * 32);

    f32x4 s[4];
    __builtin_amdgcn_s_setprio(1);
    for (int kt = 0; kt < 4; ++kt) {
      f32x4 t = {};
      for (int ks = 0; ks < 4; ++ks) t = mfma16(kf[kt][ks], qf[ks], t);
      s[kt] = t;
    }
    __builtin_amdgcn_s_setprio(0);

    // row max (max3-fused trees) + defer-max (THR = 11.5 log2-units)
    float mA = fmaxf(fmaxf(s[0][0], s[0][1]), s[0][2]);
    mA = fmaxf(fmaxf(mA, s[0][3]), s[1][0]);
    mA = fmaxf(fmaxf(mA, s[1][1]), s[1][2]);
    mA = fmaxf(mA, s[1][3]);
    float mB = fmaxf(fmaxf(s[2][0], s[2][1]), s[2][2]);
    mB = fmaxf(fmaxf(mB, s[2][3]), s[3][0]);
    mB = fmaxf(fmaxf(mB, s[3][1]), s[3][2]);
    mB = fmaxf(mB, s[3][3]);
    float mx = fmaxf(mA, mB);
    mx = fmaxf(mx, __shfl_xor(mx, 16));
    mx = fmaxf(mx, __shfl_xor(mx, 32));
    bool grow = mx > m_run + 11.5f;
    if (__ballot(grow)) {
      float mn = fmaxf(m_run, mx);
      float corr = EXP2(m_run - mn);
      m_run = mn;
      float c0 = __shfl(corr, srcq + 0), c1 = __shfl(corr, srcq + 1);
      float c2 = __shfl(corr, srcq + 2), c3 = __shfl(corr, srcq + 3);
      lsum[0] *= c0; lsum[1] *= c1; lsum[2] *= c2; lsum[3] *= c3;
      for (int nb = 0; nb < 8; ++nb) {
        acc[nb][0] *= c0; acc[nb][1] *= c1; acc[nb][2] *= c2; acc[nb][3] *= c3;
      }
    }
    for (int kt = 0; kt < 4; ++kt)
      for (int r = 0; r < 4; ++r)
        s[kt][r] = EXP2(s[kt][r] - m_run);

    // PV A-fragment = pack of own registers (PERM staging); l via mfma(af, ones)
    half8 af[2];
    for (int kst = 0; kst < 2; ++kst) {
      union { half8 h8; half2t h2[4]; } un;
      un.h2[0] = pkrtz(s[2 * kst][0], s[2 * kst][1]);
      un.h2[1] = pkrtz(s[2 * kst][2], s[2 * kst][3]);
      un.h2[2] = pkrtz(s[2 * kst + 1][0], s[2 * kst + 1][1]);
      un.h2[3] = pkrtz(s[2 * kst + 1][2], s[2 * kst + 1][3]);
      af[kst] = un.h8;
    }

    __builtin_amdgcn_s_setprio(1);
    lsum = mfma16(af[0], ones, lsum);
    lsum = mfma16(af[1], ones, lsum);
    for (int nb = 0; nb < 8; ++nb)
      for (int kst = 0; kst < 2; ++kst)
        acc[nb] = mfma16(af[kst], vf[nb][kst], acc[nb]);
    __builtin_amdgcn_s_setprio(0);
  }

  // epilogue: unnormalized acc + (m, l)
  size_t gq0 = (size_t)b * NN + q0;
  f16* A = (half ? acc1 : acc0) + gq0 * DD;
  for (int nb = 0; nb < 8; ++nb)
    for (int r = 0; r < 4; ++r)
      A[(size_t)(lg * 4 + r) * DD + nb * 16 + lr] = (f16)acc[nb][r];
  float* mArr = ml + half * 32768;
  float* lArr = ml + 65536 + half * 32768;
  if (lg == 0) mArr[gq0 + lr] = m_run;
  if (lr == 0)
    for (int r = 0; r < 4; ++r) lArr[gq0 + lg * 4 + r] = lsum[r];
}

// ---------- merge the two KV halves: Y = (acc0*c1 + acc1*c2) / (l1*c1 + l2*c2) ----------
__global__ void k_merge(const f16* __restrict__ a0, const f16* __restrict__ a1,
                        const float* __restrict__ ml, f16* __restrict__ Y) {
  int idx = blockIdx.x * 256 + threadIdx.x;  // one half8 of d per thread
  int q = idx >> 4, dc = (idx & 15) * 8;
  float m1 = ml[q], m2 = ml[32768 + q];
  float l1 = ml[65536 + q], l2 = ml[98304 + q];
  float mm = fmaxf(m1, m2);
  float c1 = EXP2(m1 - mm), c2 = EXP2(m2 - mm);
  float inv = 1.f / (l1 * c1 + l2 * c2);
  c1 *= inv; c2 *= inv;
  half8 va = *(const half8*)(a0 + (size_t)q * DD + dc);
  half8 vb = *(const half8*)(a1 + (size_t)q * DD + dc);
  half8 o;
  for (int j = 0; j < 8; ++j) o[j] = (f16)((float)va[j] * c1 + (float)vb[j] * c2);
  *(half8*)(Y + (size_t)q * DD + dc) = o;
}

// ---------- output projection + fused BN partial stats ----------
__global__ __launch_bounds__(256) void k_gemm2(const f16* __restrict__ Y, const f16* __restrict__ Wwh,
                                               const float* __restrict__ wb, float* __restrict__ wy,
                                               float* __restrict__ stats) {
  __shared__ float part[2][8][64];
  int lane = threadIdx.x & 63, wave = threadIdx.x >> 6;
  int lr = lane & 15, lg = lane >> 4;
  int wr = wave >> 1, wc = wave & 1;
  int c0 = blockIdx.y * 64 + wc * 32;
  half8 w[4][2];
  for (int k0 = 0; k0 < 4; ++k0)
    for (int j = 0; j < 2; ++j)
      w[k0][j] = *(const half8*)(Wwh + (size_t)(c0 + j * 16 + lr) * DD + k0 * 32 + lg * 8);
  float bias[2];
  for (int j = 0; j < 2; ++j) bias[j] = wb[c0 + j * 16 + lr];
  float ps[2][2] = {};
  for (int mt = 0; mt < 8; ++mt) {
    int m0 = (blockIdx.x * 8 + mt) * 64 + wr * 32;
    f32x4 acc[2][2] = {};
    for (int k0 = 0; k0 < 4; ++k0) {
      half8 a[2];
      for (int i = 0; i < 2; ++i)
        a[i] = *(const half8*)(Y + (size_t)(m0 + i * 16 + lr) * DD + k0 * 32 + lg * 8);
      for (int i = 0; i < 2; ++i)
        for (int j = 0; j < 2; ++j)
          acc[i][j] = mfma16(a[i], w[k0][j], acc[i][j]);
    }
    for (int i = 0; i < 2; ++i)
      for (int j = 0; j < 2; ++j)
        for (int r = 0; r < 4; ++r) {
          int row = m0 + i * 16 + lg * 4 + r;
          int col = c0 + j * 16 + lr;
          float v = acc[i][j][r] + bias[j];
          wy[(size_t)row * CC + col] = v;
          ps[j][0] += v;
          ps[j][1] += v * v;
        }
  }
  for (int j = 0; j < 2; ++j) {
    int colL = wc * 32 + j * 16 + lr;
    part[0][wr * 4 + lg][colL] = ps[j][0];
    part[1][wr * 4 + lg][colL] = ps[j][1];
  }
  __syncthreads();
  if (threadIdx.x < 128) {
    int metric = threadIdx.x >> 6, col = threadIdx.x & 63;
    float s = 0.f;
    for (int wtr = 0; wtr < 8; ++wtr) s += part[metric][wtr][col];
    atomicAdd(&stats[metric * CC + blockIdx.y * 64 + col], s);
  }
}

// ---------- BN apply + residual ----------
__global__ void k_bn_apply(const float* __restrict__ wy, const float* __restrict__ x,
                           const float* __restrict__ stats, const float* __restrict__ gamma,
                           const float* __restrict__ beta, float* __restrict__ out) {
  __shared__ float tile[32][33];
  int b = blockIdx.z, c0 = blockIdx.y * 32, n0 = blockIdx.x * 32;
  int tx = threadIdx.x, ty = threadIdx.y;
  for (int j = 0; j < 4; ++j) {
    int nn = ty + j * 8;
    tile[nn][tx] = wy[((size_t)b * NN + n0 + nn) * CC + c0 + tx];
  }
  __syncthreads();
  const float inv_cnt = 1.f / (float)(BB * NN);
  for (int j = 0; j < 4; ++j) {
    int cc = ty + j * 8;
    int c = c0 + cc;
    float mean = stats[c] * inv_cnt;
    float var = stats[CC + c] * inv_cnt - mean * mean;
    float scale = gamma[c] * rsqrtf(var + BN_EPS);
    size_t oi = ((size_t)b * CC + c) * NN + n0 + tx;
    out[oi] = (tile[tx][cc] - mean) * scale + beta[c] + x[oi];
  }
}

extern "C" void kernel_launch(void* const* d_in, const int* in_sizes, int n_in,
                              void* d_out, int out_size, void* d_ws, size_t ws_size,
                              hipStream_t stream) {
  const float* x = (const float*)d_in[0];
  const float* tw = (const float*)d_in[1];
  const float* pw = (const float*)d_in[2];
  const float* gw = (const float*)d_in[3];
  const float* ww = (const float*)d_in[4];
  const float* wb = (const float*)d_in[5];
  const float* gamma = (const float*)d_in[6];
  const float* beta = (const float*)d_in[7];
  float* out = (float*)d_out;
  char* ws = (char*)d_ws;

  f16* Wcat = (f16*)(ws + 0);                    // 192 KB
  f16* Wwh = (f16*)(ws + 196608);                // 64 KB
  float* stats = (float*)(ws + 262144);          // 2 KB
  float* ml = (float*)(ws + 524288);             // 512 KB: [m0|m1|l0|l1] x 32768 f32
  const size_t BASE = 1 << 20;
  f16* T = (f16*)(ws + BASE);                    // 8 MB
  f16* P = (f16*)(ws + BASE + 8388608);          // 8 MB
  f16* Gdn = (f16*)(ws + BASE + 16777216);       // 8 MB
  f16* Yb = (f16*)(ws + BASE + 25165824);        // 8 MB (acc0, merged in-place -> Y)
  f16* xT = (f16*)(ws + BASE + 33554432);        // 16 MB (dead after gemm1)
  f16* Gnd = (f16*)(ws + BASE + 50331648);       // 8 MB (dead after transpose_g)
  f16* acc1 = (f16*)(ws + BASE + 58720256);      // 8 MB (dead after merge)
  float* wy = (float*)(ws + BASE + 33554432);    // 32 MB (reuses xT+Gnd+acc1 after merge)

  k_cast_weights<<<512, 256, 0, stream>>>(tw, pw, gw, ww, Wcat, Wwh, stats);
  k_transpose_x<<<dim3(NN / 32, CC / 32, BB), dim3(32, 8), 0, stream>>>(x, xT);
  k_gemm1<<<dim3(NN / 64, 384 / 64, BB), 256, 0, stream>>>(xT, Wcat, T, P, Gnd);
  k_transpose_g<<<dim3(NN / 32, DD / 32, BB), dim3(32, 8), 0, stream>>>(Gnd, Gdn);
  k_flash<<<1024, 256, 0, stream>>>(T, P, Gdn, Yb, acc1, ml);
  k_merge<<<2048, 256, 0, stream>>>(Yb, acc1, ml, Yb);
  k_gemm2<<<dim3(BB * NN / 512, CC / 64), 256, 0, stream>>>(Yb, Wwh, wb, wy, stats);
  k_bn_apply<<<dim3(NN / 32, CC / 32, BB), dim3(32, 8), 0, stream>>>(wy, x, stats, gamma, beta, out);
}

// Round 8
// 182.312 us; speedup vs baseline: 3.0568x; 3.0568x over previous
//
#include <hip/hip_runtime.h>

#define BB 8
#define CC 256
#define DD 128
#define NN 4096
#define BN_EPS 1e-5f

typedef _Float16 f16;
typedef _Float16 half8 __attribute__((ext_vector_type(8)));
typedef _Float16 half2t __attribute__((ext_vector_type(2)));
typedef float f32x4 __attribute__((ext_vector_type(4)));

__device__ __forceinline__ f32x4 mfma16(half8 a, half8 b, f32x4 c) {
  return __builtin_amdgcn_mfma_f32_16x16x32_f16(a, b, c, 0, 0, 0);
}

__device__ __forceinline__ void gload_lds16(const void* g, void* l) {
  __builtin_amdgcn_global_load_lds((const __attribute__((address_space(1))) void*)g,
                                   (__attribute__((address_space(3))) void*)l, 16, 0, 0);
}

__device__ __forceinline__ half2t pkrtz(float a, float b) {
  auto t = __builtin_amdgcn_cvt_pkrtz(a, b);
  return __builtin_bit_cast(half2t, t);
}

#define EXP2(x) __builtin_amdgcn_exp2f(x)

// key permutation: swapped-QK register layout feeds PV A-fragment with zero data movement
#define PERM(i) ((((i) >> 5) & 1) * 32 + (((i) >> 2) & 3) * 8 + (((i) >> 4) & 1) * 4 + ((i) & 3))

// ---------- weights cast (fp32 -> fp16), stats zero ----------
__global__ void k_cast_weights(const float* __restrict__ tw, const float* __restrict__ pw,
                               const float* __restrict__ gw, const float* __restrict__ ww,
                               f16* __restrict__ Wcat, f16* __restrict__ Wwh,
                               float* __restrict__ stats) {
  int i = blockIdx.x * 256 + threadIdx.x;
  if (i < 32768) Wcat[i] = (f16)tw[i];
  else if (i < 65536) Wcat[i] = (f16)pw[i - 32768];
  else if (i < 98304) Wcat[i] = (f16)gw[i - 65536];
  else if (i < 131072) Wwh[i - 98304] = (f16)ww[i - 98304];
  if (i < 512) stats[i] = 0.f;
}

// ---------- x [B][C][N] f32 -> xT [B][N][C] f16 ----------
__global__ void k_transpose_x(const float* __restrict__ x, f16* __restrict__ xT) {
  __shared__ f16 tile[32][33];
  int b = blockIdx.z, c0 = blockIdx.y * 32, n0 = blockIdx.x * 32;
  int tx = threadIdx.x, ty = threadIdx.y;
  const float* xp = x + ((size_t)b * CC + c0) * NN + n0;
  for (int j = 0; j < 4; ++j) {
    int cc = ty + j * 8;
    tile[cc][tx] = (f16)xp[(size_t)cc * NN + tx];
  }
  __syncthreads();
  f16* xo = xT + ((size_t)b * NN + n0) * CC + c0;
  for (int j = 0; j < 4; ++j) {
    int nn = ty + j * 8;
    xo[(size_t)nn * CC + tx] = tile[tx][nn];
  }
}

// ---------- projections: A-fragments in registers, all 384 out-channels per block ----------
// xT read ONCE (32MB total); Wcat (192KB) stays L2-resident across all 512 blocks.
__global__ __launch_bounds__(256) void k_gemm1(const f16* __restrict__ xT, const f16* __restrict__ Wcat,
                                               f16* __restrict__ T, f16* __restrict__ P,
                                               f16* __restrict__ Gnd) {
  int b = blockIdx.y;
  int lane = threadIdx.x & 63, wave = threadIdx.x >> 6;
  int lr = lane & 15, lg = lane >> 4;
  int wr = wave >> 1, wc = wave & 1;
  int m0 = blockIdx.x * 64 + wr * 32;
  const f16* A = xT + (size_t)b * NN * CC;
  half8 a[2][8];
#pragma unroll
  for (int i = 0; i < 2; ++i)
#pragma unroll
    for (int k0 = 0; k0 < 8; ++k0)
      a[i][k0] = *(const half8*)(A + (size_t)(m0 + i * 16 + lr) * CC + k0 * 32 + lg * 8);
  size_t base = (size_t)b * NN;
#pragma unroll
  for (int yb = 0; yb < 6; ++yb) {
    int c0 = yb * 64 + wc * 32;
    f32x4 acc[2][2] = {};
#pragma unroll
    for (int k0 = 0; k0 < 8; ++k0) {
      half8 w[2];
      for (int j = 0; j < 2; ++j)
        w[j] = *(const half8*)(Wcat + (size_t)(c0 + j * 16 + lr) * CC + k0 * 32 + lg * 8);
      for (int i = 0; i < 2; ++i)
        for (int j = 0; j < 2; ++j)
          acc[i][j] = mfma16(a[i][k0], w[j], acc[i][j]);
    }
    f16* dst = (yb < 2) ? T : (yb < 4) ? P : Gnd;
    int cl0 = (yb & 1) * 64 + wc * 32;
    for (int i = 0; i < 2; ++i)
      for (int j = 0; j < 2; ++j)
        for (int r = 0; r < 4; ++r) {
          int row = m0 + i * 16 + lg * 4 + r;
          int col = cl0 + j * 16 + lr;
          dst[(base + row) * DD + col] = (f16)acc[i][j][r];
        }
  }
}

// ---------- Gnd [B][N][D] -> Gdn [B][D][N] ----------
__global__ void k_transpose_g(const f16* __restrict__ Gnd, f16* __restrict__ Gdn) {
  __shared__ f16 tile[32][33];
  int b = blockIdx.z, d0 = blockIdx.y * 32, n0 = blockIdx.x * 32;
  int tx = threadIdx.x, ty = threadIdx.y;
  for (int j = 0; j < 4; ++j) {
    int nn = ty + j * 8;
    tile[nn][tx] = Gnd[((size_t)b * NN + n0 + nn) * DD + d0 + tx];
  }
  __syncthreads();
  for (int j = 0; j < 4; ++j) {
    int dd = ty + j * 8;
    Gdn[((size_t)b * DD + d0 + dd) * NN + n0 + tx] = tile[tx][dd];
  }
}

// ---------- flash attention (round-6 structure + lsum-via-MFMA + hoisted staging) ----------
// 4 waves/block, 16 q/wave; KV block 64; K dbuf 2x16KB + V dbuf 2x16KB swizzled = 64KB.
// 2 barriers/iter, counted vmcnt(8). Swapped QK (mfma(K,Q)), PERM'd K rows ->
// PV A-frag = pack of own regs; l accumulated by mfma(af, ones) in acc layout.
__global__ __launch_bounds__(256) void k_flash(const f16* __restrict__ T, const f16* __restrict__ P,
                                               const f16* __restrict__ Gdn, f16* __restrict__ Y) {
  __shared__ char smem[65536];
  int bid = blockIdx.x;
  int b = bid & 7;  // batch -> XCD pinning
  int qx = bid >> 3;
  int tid = threadIdx.x;
  int lane = tid & 63, wave = tid >> 6;
  int lr = lane & 15, lg = lane >> 4;
  int q0 = qx * 64 + wave * 16;
  const f16* Tb = T + (size_t)b * NN * DD;
  const f16* Pb = P + (size_t)b * NN * DD;
  const f16* Vb = Gdn + (size_t)b * DD * NN;
  int srcq = 4 * lg;

  // hoisted per-thread staging bases (invariant); in-loop adds are uniform strides only
  const f16* kbase[4];
  const f16* vbase[4];
  char* kdst[4];
  char* vdst[4];
#pragma unroll
  for (int inst = 0; inst < 4; ++inst) {
    int t = inst * 256 + tid;
    int row = t >> 4, sp = t & 15, sl = sp ^ (row & 7);
    kbase[inst] = Pb + (size_t)PERM(row) * DD + sl * 8;
    kdst[inst] = smem + (inst * 256 + wave * 64) * 16;
    int rv = t >> 3, spv = t & 7, slv = spv ^ (rv & 7);
    vbase[inst] = Vb + (size_t)rv * NN + slv * 8;
    vdst[inst] = smem + 32768 + (inst * 256 + wave * 64) * 16;
  }

  half8 qf[4];
  for (int ks = 0; ks < 4; ++ks) {
    half8 v = *(const half8*)(Tb + (size_t)(q0 + lr) * DD + ks * 32 + lg * 8);
    for (int j = 0; j < 8; ++j) v[j] *= (f16)1.44269504f;  // log2(e) into Q
    qf[ks] = v;
  }
  half8 ones;
  for (int j = 0; j < 8; ++j) ones[j] = (f16)1.f;

  f32x4 acc[8] = {};
  f32x4 lsum = {};
  float m_run = -1e30f;

  // prologue: K(0), V(0) into buffer 0
#pragma unroll
  for (int inst = 0; inst < 4; ++inst) gload_lds16(kbase[inst], kdst[inst]);
#pragma unroll
  for (int inst = 0; inst < 4; ++inst) gload_lds16(vbase[inst], vdst[inst]);

  for (int kb = 0; kb < 64; ++kb) {
    int keyn = (kb < 63) ? kb * 64 + 64 : 0;  // last prefetch harmless
    int cur = (kb & 1) * 16384, nxt = ((kb + 1) & 1) * 16384;
    char* Kc = smem + cur;
    char* Vc = smem + 32768 + cur;

    // issue K(kb+1); target buffer's last reader (QK kb-1) finished before B2(kb-1)
    size_t ko = (size_t)keyn * DD;
#pragma unroll
    for (int inst = 0; inst < 4; ++inst) gload_lds16(kbase[inst] + ko, kdst[inst] + nxt);
    asm volatile("s_waitcnt vmcnt(8)" ::: "memory");  // K(kb) done; V(kb)+K(kb+1) in flight
    __builtin_amdgcn_sched_barrier(0);
    __builtin_amdgcn_s_barrier();  // B1
    __builtin_amdgcn_sched_barrier(0);

    // QK^T swapped: s[kt][r] = S[key perm(16kt+4lg+r)][q0+lr]
    f32x4 s[4];
    __builtin_amdgcn_s_setprio(1);
    for (int kt = 0; kt < 4; ++kt) {
      f32x4 t = {};
      for (int ks = 0; ks < 4; ++ks) {
        half8 kf = *(const half8*)(Kc + (kt * 16 + lr) * 256 + (((ks * 4 + lg) ^ (lr & 7)) << 4));
        t = mfma16(kf, qf[ks], t);
      }
      s[kt] = t;
    }
    __builtin_amdgcn_s_setprio(0);

    // row max (max3-fused tree) + defer-max (THR = 11.5 log2-units)
    float mA = fmaxf(fmaxf(s[0][0], s[0][1]), s[0][2]);
    mA = fmaxf(fmaxf(mA, s[0][3]), s[1][0]);
    mA = fmaxf(fmaxf(mA, s[1][1]), s[1][2]);
    mA = fmaxf(mA, s[1][3]);
    float mB = fmaxf(fmaxf(s[2][0], s[2][1]), s[2][2]);
    mB = fmaxf(fmaxf(mB, s[2][3]), s[3][0]);
    mB = fmaxf(fmaxf(mB, s[3][1]), s[3][2]);
    mB = fmaxf(mB, s[3][3]);
    float mx = fmaxf(mA, mB);
    mx = fmaxf(mx, __shfl_xor(mx, 16));
    mx = fmaxf(mx, __shfl_xor(mx, 32));
    bool grow = mx > m_run + 11.5f;
    if (__ballot(grow)) {
      float mn = fmaxf(m_run, mx);
      float corr = EXP2(m_run - mn);
      m_run = mn;
      float c0 = __shfl(corr, srcq + 0), c1 = __shfl(corr, srcq + 1);
      float c2 = __shfl(corr, srcq + 2), c3 = __shfl(corr, srcq + 3);
      lsum[0] *= c0; lsum[1] *= c1; lsum[2] *= c2; lsum[3] *= c3;
      for (int nb = 0; nb < 8; ++nb) {
        acc[nb][0] *= c0; acc[nb][1] *= c1; acc[nb][2] *= c2; acc[nb][3] *= c3;
      }
    }
    for (int kt = 0; kt < 4; ++kt)
      for (int r = 0; r < 4; ++r)
        s[kt][r] = EXP2(s[kt][r] - m_run);

    // PV A-fragment = pack of own registers (PERM staging)
    half8 af[2];
    for (int kst = 0; kst < 2; ++kst) {
      union { half8 h8; half2t h2[4]; } un;
      un.h2[0] = pkrtz(s[2 * kst][0], s[2 * kst][1]);
      un.h2[1] = pkrtz(s[2 * kst][2], s[2 * kst][3]);
      un.h2[2] = pkrtz(s[2 * kst + 1][0], s[2 * kst + 1][1]);
      un.h2[3] = pkrtz(s[2 * kst + 1][2], s[2 * kst + 1][3]);
      af[kst] = un.h8;
    }
    // l accumulation on the MFMA pipe (same C-layout as acc)
    lsum = mfma16(af[0], ones, lsum);
    lsum = mfma16(af[1], ones, lsum);

    // issue V(kb+1); target buffer's last reader (PV kb-1) finished before B1(kb)
#pragma unroll
    for (int inst = 0; inst < 4; ++inst) gload_lds16(vbase[inst] + keyn, vdst[inst] + nxt);
    asm volatile("s_waitcnt vmcnt(8)" ::: "memory");  // V(kb) done; K/V(kb+1) in flight
    __builtin_amdgcn_sched_barrier(0);
    __builtin_amdgcn_s_barrier();  // B2
    __builtin_amdgcn_sched_barrier(0);

    __builtin_amdgcn_s_setprio(1);
    for (int nb = 0; nb < 8; ++nb)
      for (int kst = 0; kst < 2; ++kst) {
        half8 vf = *(const half8*)(Vc + (nb * 16 + lr) * 128 + (((kst * 4 + lg) ^ (lr & 7)) << 4));
        acc[nb] = mfma16(af[kst], vf, acc[nb]);
      }
    __builtin_amdgcn_s_setprio(0);
  }
  asm volatile("s_waitcnt vmcnt(0)" ::: "memory");

  float il[4];
  for (int r = 0; r < 4; ++r) il[r] = 1.f / lsum[r];
  f16* Yb = Y + (size_t)b * NN * DD;
  for (int nb = 0; nb < 8; ++nb)
    for (int r = 0; r < 4; ++r)
      Yb[(size_t)(q0 + lg * 4 + r) * DD + nb * 16 + lr] = (f16)(acc[nb][r] * il[r]);
}

// ---------- output projection + fused BN partial stats (wy stored f16) ----------
__global__ __launch_bounds__(256) void k_gemm2(const f16* __restrict__ Y, const f16* __restrict__ Wwh,
                                               const float* __restrict__ wb, f16* __restrict__ wy,
                                               float* __restrict__ stats) {
  __shared__ float part[2][8][64];
  int lane = threadIdx.x & 63, wave = threadIdx.x >> 6;
  int lr = lane & 15, lg = lane >> 4;
  int wr = wave >> 1, wc = wave & 1;
  int c0 = blockIdx.y * 64 + wc * 32;
  half8 w[4][2];
  for (int k0 = 0; k0 < 4; ++k0)
    for (int j = 0; j < 2; ++j)
      w[k0][j] = *(const half8*)(Wwh + (size_t)(c0 + j * 16 + lr) * DD + k0 * 32 + lg * 8);
  float bias[2];
  for (int j = 0; j < 2; ++j) bias[j] = wb[c0 + j * 16 + lr];
  float ps[2][2] = {};
  for (int mt = 0; mt < 8; ++mt) {
    int m0 = (blockIdx.x * 8 + mt) * 64 + wr * 32;
    f32x4 acc[2][2] = {};
    for (int k0 = 0; k0 < 4; ++k0) {
      half8 a[2];
      for (int i = 0; i < 2; ++i)
        a[i] = *(const half8*)(Y + (size_t)(m0 + i * 16 + lr) * DD + k0 * 32 + lg * 8);
      for (int i = 0; i < 2; ++i)
        for (int j = 0; j < 2; ++j)
          acc[i][j] = mfma16(a[i], w[k0][j], acc[i][j]);
    }
    for (int i = 0; i < 2; ++i)
      for (int j = 0; j < 2; ++j)
        for (int r = 0; r < 4; ++r) {
          int row = m0 + i * 16 + lg * 4 + r;
          int col = c0 + j * 16 + lr;
          float v = acc[i][j][r] + bias[j];
          wy[(size_t)row * CC + col] = (f16)v;
          ps[j][0] += v;
          ps[j][1] += v * v;
        }
  }
  for (int j = 0; j < 2; ++j) {
    int colL = wc * 32 + j * 16 + lr;
    part[0][wr * 4 + lg][colL] = ps[j][0];
    part[1][wr * 4 + lg][colL] = ps[j][1];
  }
  __syncthreads();
  if (threadIdx.x < 128) {
    int metric = threadIdx.x >> 6, col = threadIdx.x & 63;
    float s = 0.f;
    for (int wtr = 0; wtr < 8; ++wtr) s += part[metric][wtr][col];
    atomicAdd(&stats[metric * CC + blockIdx.y * 64 + col], s);
  }
}

// ---------- BN apply + residual ----------
__global__ void k_bn_apply(const f16* __restrict__ wy, const float* __restrict__ x,
                           const float* __restrict__ stats, const float* __restrict__ gamma,
                           const float* __restrict__ beta, float* __restrict__ out) {
  __shared__ f16 tile[32][33];
  int b = blockIdx.z, c0 = blockIdx.y * 32, n0 = blockIdx.x * 32;
  int tx = threadIdx.x, ty = threadIdx.y;
  for (int j = 0; j < 4; ++j) {
    int nn = ty + j * 8;
    tile[nn][tx] = wy[((size_t)b * NN + n0 + nn) * CC + c0 + tx];
  }
  __syncthreads();
  const float inv_cnt = 1.f / (float)(BB * NN);
  for (int j = 0; j < 4; ++j) {
    int cc = ty + j * 8;
    int c = c0 + cc;
    float mean = stats[c] * inv_cnt;
    float var = stats[CC + c] * inv_cnt - mean * mean;
    float scale = gamma[c] * rsqrtf(var + BN_EPS);
    size_t oi = ((size_t)b * CC + c) * NN + n0 + tx;
    out[oi] = ((float)tile[tx][cc] - mean) * scale + beta[c] + x[oi];
  }
}

extern "C" void kernel_launch(void* const* d_in, const int* in_sizes, int n_in,
                              void* d_out, int out_size, void* d_ws, size_t ws_size,
                              hipStream_t stream) {
  const float* x = (const float*)d_in[0];
  const float* tw = (const float*)d_in[1];
  const float* pw = (const float*)d_in[2];
  const float* gw = (const float*)d_in[3];
  const float* ww = (const float*)d_in[4];
  const float* wb = (const float*)d_in[5];
  const float* gamma = (const float*)d_in[6];
  const float* beta = (const float*)d_in[7];
  float* out = (float*)d_out;
  char* ws = (char*)d_ws;

  f16* Wcat = (f16*)(ws + 0);                    // 192 KB
  f16* Wwh = (f16*)(ws + 196608);                // 64 KB
  float* stats = (float*)(ws + 262144);          // 2 KB
  const size_t BASE = 1 << 20;
  f16* T = (f16*)(ws + BASE);                    // 8 MB
  f16* P = (f16*)(ws + BASE + 8388608);          // 8 MB
  f16* Gdn = (f16*)(ws + BASE + 16777216);       // 8 MB
  f16* Yb = (f16*)(ws + BASE + 25165824);        // 8 MB
  f16* xT = (f16*)(ws + BASE + 33554432);        // 16 MB (dead after gemm1)
  f16* Gnd = (f16*)(ws + BASE + 50331648);       // 8 MB (dead after transpose_g)
  f16* wy = (f16*)(ws + BASE + 33554432);        // 16 MB f16 (reuses xT region)

  k_cast_weights<<<512, 256, 0, stream>>>(tw, pw, gw, ww, Wcat, Wwh, stats);
  k_transpose_x<<<dim3(NN / 32, CC / 32, BB), dim3(32, 8), 0, stream>>>(x, xT);
  k_gemm1<<<dim3(NN / 64, BB), 256, 0, stream>>>(xT, Wcat, T, P, Gnd);
  k_transpose_g<<<dim3(NN / 32, DD / 32, BB), dim3(32, 8), 0, stream>>>(Gnd, Gdn);
  k_flash<<<512, 256, 0, stream>>>(T, P, Gdn, Yb);
  k_gemm2<<<dim3(BB * NN / 512, CC / 64), 256, 0, stream>>>(Yb, Wwh, wb, wy, stats);
  k_bn_apply<<<dim3(NN / 32, CC / 32, BB), dim3(32, 8), 0, stream>>>(wy, x, stats, gamma, beta, out);
}

// Round 9
// 175.895 us; speedup vs baseline: 3.1683x; 1.0365x over previous
//
#include <hip/hip_runtime.h>

#define BB 8
#define CC 256
#define DD 128
#define NN 4096
#define BN_EPS 1e-5f

typedef _Float16 f16;
typedef _Float16 half8 __attribute__((ext_vector_type(8)));
typedef _Float16 half2t __attribute__((ext_vector_type(2)));
typedef float f32x4 __attribute__((ext_vector_type(4)));

__device__ __forceinline__ f32x4 mfma16(half8 a, half8 b, f32x4 c) {
  return __builtin_amdgcn_mfma_f32_16x16x32_f16(a, b, c, 0, 0, 0);
}

__device__ __forceinline__ void gload_lds16(const void* g, void* l) {
  __builtin_amdgcn_global_load_lds((const __attribute__((address_space(1))) void*)g,
                                   (__attribute__((address_space(3))) void*)l, 16, 0, 0);
}

__device__ __forceinline__ half2t pkrtz(float a, float b) {
  auto t = __builtin_amdgcn_cvt_pkrtz(a, b);
  return __builtin_bit_cast(half2t, t);
}

#define EXP2(x) __builtin_amdgcn_exp2f(x)

// key permutation for 32-key tiles: swapped-QK register layout feeds PV A-frag directly.
// i bits: i4, i3i2, i1i0 -> PERM32 = 8*(i3i2) + 4*i4 + (i1i0)
#define PERM32(i) ((((i) >> 2) & 3) * 8 + (((i) >> 4) & 1) * 4 + ((i) & 3))

// ---------- weights cast (fp32 -> fp16), stats zero ----------
__global__ void k_cast_weights(const float* __restrict__ tw, const float* __restrict__ pw,
                               const float* __restrict__ gw, const float* __restrict__ ww,
                               f16* __restrict__ Wcat, f16* __restrict__ Wwh,
                               float* __restrict__ stats) {
  int i = blockIdx.x * 256 + threadIdx.x;
  if (i < 32768) Wcat[i] = (f16)tw[i];
  else if (i < 65536) Wcat[i] = (f16)pw[i - 32768];
  else if (i < 98304) Wcat[i] = (f16)gw[i - 65536];
  else if (i < 131072) Wwh[i - 98304] = (f16)ww[i - 98304];
  if (i < 512) stats[i] = 0.f;
}

// ---------- fused projections: x staged+transposed in LDS, G transposed in LDS ----------
// replaces transpose_x + gemm1 + transpose_g. Per block: 64 n-rows, all 384 out-channels.
__global__ __launch_bounds__(256) void k_gemm1(const float* __restrict__ x, const f16* __restrict__ Wcat,
                                               f16* __restrict__ T, f16* __restrict__ P,
                                               f16* __restrict__ Gdn) {
  __shared__ char xls[32768];  // xl[n 64][c 256] f16, granule-swizzled
  __shared__ char gls[16384];  // gl[n 64][d 128] f16, granule-swizzled
  int b = blockIdx.y;
  int n0 = blockIdx.x * 64;
  int tid = threadIdx.x;
  int lane = tid & 63, wave = tid >> 6;
  int lr = lane & 15, lg = lane >> 4;
  int wr = wave >> 1, wc = wave & 1;

  // stage x[b][c][n0..n0+64) -> xl[n][c] f16 (swizzle: granule (c>>3) ^ (n&7))
  {
    int c = tid;
    const float* src = x + ((size_t)b * CC + c) * NN + n0;
#pragma unroll
    for (int n4 = 0; n4 < 64; n4 += 4) {
      f32x4 v = *(const f32x4*)(src + n4);
#pragma unroll
      for (int k = 0; k < 4; ++k) {
        int n = n4 + k;
        *(f16*)(xls + n * 512 + ((((c >> 3) ^ (n & 7)) * 8 + (c & 7)) * 2)) = (f16)v[k];
      }
    }
  }
  __syncthreads();

  // A-fragments from LDS
  half8 a[2][8];
#pragma unroll
  for (int i = 0; i < 2; ++i) {
    int nloc = wr * 32 + i * 16 + lr;
#pragma unroll
    for (int k0 = 0; k0 < 8; ++k0)
      a[i][k0] = *(const half8*)(xls + nloc * 512 + (((k0 * 4 + lg) ^ (nloc & 7)) << 4));
  }

  size_t base = (size_t)b * NN + n0;
#pragma unroll
  for (int yb = 0; yb < 6; ++yb) {
    int c0 = yb * 64 + wc * 32;
    f32x4 acc[2][2] = {};
#pragma unroll
    for (int k0 = 0; k0 < 8; ++k0) {
      half8 w[2];
      for (int j = 0; j < 2; ++j)
        w[j] = *(const half8*)(Wcat + (size_t)(c0 + j * 16 + lr) * CC + k0 * 32 + lg * 8);
      for (int i = 0; i < 2; ++i)
        for (int j = 0; j < 2; ++j)
          acc[i][j] = mfma16(a[i][k0], w[j], acc[i][j]);
    }
    if (yb < 4) {
      f16* dst = (yb < 2) ? T : P;
      int cl0 = (yb & 1) * 64 + wc * 32;
      for (int i = 0; i < 2; ++i)
        for (int j = 0; j < 2; ++j)
          for (int r = 0; r < 4; ++r) {
            int row = wr * 32 + i * 16 + lg * 4 + r;
            int col = cl0 + j * 16 + lr;
            dst[(base + row) * DD + col] = (f16)acc[i][j][r];
          }
    } else {
      // G channels -> gl[n][d] (swizzle: granule (d>>3) ^ (n&7))
      for (int i = 0; i < 2; ++i)
        for (int j = 0; j < 2; ++j)
          for (int r = 0; r < 4; ++r) {
            int n = wr * 32 + i * 16 + lg * 4 + r;
            int d = (yb - 4) * 64 + wc * 32 + j * 16 + lr;
            *(f16*)(gls + n * 256 + ((((d >> 3) ^ (n & 7)) * 8 + (d & 7)) * 2)) = (f16)acc[i][j][r];
          }
    }
  }
  __syncthreads();
  // write Gdn[b][d][n0..n0+64) coalesced from gl
  {
    int d = tid >> 1, nh = (tid & 1) * 32;
    f16 tmp[32];
#pragma unroll
    for (int k = 0; k < 32; ++k) {
      int n = nh + k;
      tmp[k] = *(const f16*)(gls + n * 256 + ((((d >> 3) ^ (n & 7)) * 8 + (d & 7)) * 2));
    }
    f16* dst = Gdn + ((size_t)b * DD + d) * NN + n0 + nh;
#pragma unroll
    for (int k = 0; k < 4; ++k)
      *(half8*)(dst + k * 8) = *(const half8*)(tmp + k * 8);
  }
}

// ---------- flash attention: KVBLK=32, KV-split x2, 32KB LDS -> 4 blocks/CU ----------
// 1024 blocks (b = bid&7 -> XCD pin), 4 waves/block, 16 q/wave, 64 iters of 32 keys.
// K dbuf 2x8KB (PERM32'd rows, XOR-swizzled) + V dbuf 2x8KB (granule-swizzled).
// 2 barriers/iter, counted vmcnt(4). Swapped QK; l via mfma(af, ones).
// Outputs UNNORMALIZED f16 acc + (m, l) per q; k_merge combines halves.
__global__ __launch_bounds__(256, 4) void k_flash(const f16* __restrict__ T, const f16* __restrict__ P,
                                                  const f16* __restrict__ Gdn, f16* __restrict__ acc0,
                                                  f16* __restrict__ acc1, float* __restrict__ ml) {
  __shared__ char smem[32768];
  int bid = blockIdx.x;
  int b = bid & 7;
  int u = bid >> 3;
  int hf = u & 1;
  int qx = u >> 1;
  int tid = threadIdx.x;
  int lane = tid & 63, wave = tid >> 6;
  int lr = lane & 15, lg = lane >> 4;
  int q0 = qx * 64 + wave * 16;
  const f16* Tb = T + (size_t)b * NN * DD;
  const f16* Pb = P + ((size_t)b * NN + hf * 2048) * DD;
  const f16* Vb = Gdn + (size_t)b * DD * NN + hf * 2048;
  int srcq = 4 * lg;

  // hoisted staging bases; LDS dst is wave-uniform base (+ lane*16 by HW)
  const f16* kbase[2];
  const f16* vbase[2];
  char* kdst[2];
  char* vdst[2];
#pragma unroll
  for (int inst = 0; inst < 2; ++inst) {
    int t = inst * 256 + tid;
    int row = t >> 4, sp = t & 15, sl = sp ^ (row & 7);
    kbase[inst] = Pb + (size_t)PERM32(row) * DD + sl * 8;
    kdst[inst] = smem + (inst * 256 + wave * 64) * 16;
    int dv = t >> 2, gv = t & 3, glv = gv ^ ((dv >> 1) & 3);
    vbase[inst] = Vb + (size_t)dv * NN + glv * 8;
    vdst[inst] = smem + 16384 + (inst * 256 + wave * 64) * 16;
  }

  half8 qf[4];
  for (int ks = 0; ks < 4; ++ks) {
    half8 v = *(const half8*)(Tb + (size_t)(q0 + lr) * DD + ks * 32 + lg * 8);
    for (int j = 0; j < 8; ++j) v[j] *= (f16)1.44269504f;  // log2(e) into Q
    qf[ks] = v;
  }
  half8 ones;
  for (int j = 0; j < 8; ++j) ones[j] = (f16)1.f;

  f32x4 acc[8] = {};
  f32x4 lsum = {};
  float m_run = -1e30f;

  // prologue: K(0), V(0)
#pragma unroll
  for (int inst = 0; inst < 2; ++inst) gload_lds16(kbase[inst], kdst[inst]);
#pragma unroll
  for (int inst = 0; inst < 2; ++inst) gload_lds16(vbase[inst], vdst[inst]);

  for (int kb = 0; kb < 64; ++kb) {
    int keyn = (kb < 63) ? kb * 32 + 32 : 0;  // last prefetch harmless
    int cur = (kb & 1) * 8192, nxt = ((kb + 1) & 1) * 8192;
    char* Kc = smem + cur;
    char* Vc = smem + 16384 + cur;

    // issue K(kb+1); target buffer's last reader (QK kb-1) done before B2(kb-1)
    size_t ko = (size_t)keyn * DD;
#pragma unroll
    for (int inst = 0; inst < 2; ++inst) gload_lds16(kbase[inst] + ko, kdst[inst] + nxt);
    asm volatile("s_waitcnt vmcnt(4)" ::: "memory");  // K(kb) done; V(kb)+K(kb+1) in flight
    __builtin_amdgcn_sched_barrier(0);
    __builtin_amdgcn_s_barrier();  // B1
    __builtin_amdgcn_sched_barrier(0);

    // QK^T swapped: s[kt][r] = S[key PERM32(16kt+4lg+r)][q0+lr]
    f32x4 s[2];
    __builtin_amdgcn_s_setprio(1);
    for (int kt = 0; kt < 2; ++kt) {
      f32x4 t = {};
      for (int ks = 0; ks < 4; ++ks) {
        half8 kf = *(const half8*)(Kc + (kt * 16 + lr) * 256 + (((ks * 4 + lg) ^ (lr & 7)) << 4));
        t = mfma16(kf, qf[ks], t);
      }
      s[kt] = t;
    }
    __builtin_amdgcn_s_setprio(0);

    // row max + defer-max (THR = 11.5 log2-units)
    float mx = fmaxf(fmaxf(s[0][0], s[0][1]), fmaxf(s[0][2], s[0][3]));
    mx = fmaxf(mx, fmaxf(fmaxf(s[1][0], s[1][1]), fmaxf(s[1][2], s[1][3])));
    mx = fmaxf(mx, __shfl_xor(mx, 16));
    mx = fmaxf(mx, __shfl_xor(mx, 32));
    bool grow = mx > m_run + 11.5f;
    if (__ballot(grow)) {
      float mn = fmaxf(m_run, mx);
      float corr = EXP2(m_run - mn);
      m_run = mn;
      float c0 = __shfl(corr, srcq + 0), c1 = __shfl(corr, srcq + 1);
      float c2 = __shfl(corr, srcq + 2), c3 = __shfl(corr, srcq + 3);
      lsum[0] *= c0; lsum[1] *= c1; lsum[2] *= c2; lsum[3] *= c3;
      for (int nb = 0; nb < 8; ++nb) {
        acc[nb][0] *= c0; acc[nb][1] *= c1; acc[nb][2] *= c2; acc[nb][3] *= c3;
      }
    }
    for (int kt = 0; kt < 2; ++kt)
      for (int r = 0; r < 4; ++r)
        s[kt][r] = EXP2(s[kt][r] - m_run);

    // PV A-fragment = pack of own registers (PERM32 staging); l via mfma(af, ones)
    half8 af;
    {
      union { half8 h8; half2t h2[4]; } un;
      un.h2[0] = pkrtz(s[0][0], s[0][1]);
      un.h2[1] = pkrtz(s[0][2], s[0][3]);
      un.h2[2] = pkrtz(s[1][0], s[1][1]);
      un.h2[3] = pkrtz(s[1][2], s[1][3]);
      af = un.h8;
    }
    lsum = mfma16(af, ones, lsum);

    // issue V(kb+1); target buffer's last reader (PV kb-1) done before B1(kb)
#pragma unroll
    for (int inst = 0; inst < 2; ++inst) gload_lds16(vbase[inst] + keyn, vdst[inst] + nxt);
    asm volatile("s_waitcnt vmcnt(4)" ::: "memory");  // V(kb) done; K/V(kb+1) in flight
    __builtin_amdgcn_sched_barrier(0);
    __builtin_amdgcn_s_barrier();  // B2
    __builtin_amdgcn_sched_barrier(0);

    __builtin_amdgcn_s_setprio(1);
    for (int nb = 0; nb < 8; ++nb) {
      int d = nb * 16 + lr;
      half8 vf = *(const half8*)(Vc + d * 64 + ((lg ^ ((d >> 1) & 3)) << 4));
      acc[nb] = mfma16(af, vf, acc[nb]);
    }
    __builtin_amdgcn_s_setprio(0);
  }
  asm volatile("s_waitcnt vmcnt(0)" ::: "memory");

  // epilogue: unnormalized acc + (m, l)
  size_t gq0 = (size_t)b * NN + q0;
  f16* A = (hf ? acc1 : acc0) + gq0 * DD;
  for (int nb = 0; nb < 8; ++nb)
    for (int r = 0; r < 4; ++r)
      A[(size_t)(lg * 4 + r) * DD + nb * 16 + lr] = (f16)acc[nb][r];
  float* mArr = ml + hf * 32768;
  float* lArr = ml + 65536 + hf * 32768;
  if (lg == 0) mArr[gq0 + lr] = m_run;
  if (lr == 0)
    for (int r = 0; r < 4; ++r) lArr[gq0 + lg * 4 + r] = lsum[r];
}

// ---------- merge the two KV halves ----------
__global__ void k_merge(const f16* __restrict__ a0, const f16* __restrict__ a1,
                        const float* __restrict__ ml, f16* __restrict__ Y) {
  int idx = blockIdx.x * 256 + threadIdx.x;  // one half8 of d per thread
  int q = idx >> 4, dc = (idx & 15) * 8;
  float m1 = ml[q], m2 = ml[32768 + q];
  float l1 = ml[65536 + q], l2 = ml[98304 + q];
  float mm = fmaxf(m1, m2);
  float c1 = EXP2(m1 - mm), c2 = EXP2(m2 - mm);
  float inv = 1.f / (l1 * c1 + l2 * c2);
  c1 *= inv; c2 *= inv;
  half8 va = *(const half8*)(a0 + (size_t)q * DD + dc);
  half8 vb = *(const half8*)(a1 + (size_t)q * DD + dc);
  half8 o;
  for (int j = 0; j < 8; ++j) o[j] = (f16)((float)va[j] * c1 + (float)vb[j] * c2);
  *(half8*)(Y + (size_t)q * DD + dc) = o;
}

// ---------- output projection + fused BN partial stats (wy stored f16) ----------
__global__ __launch_bounds__(256) void k_gemm2(const f16* __restrict__ Y, const f16* __restrict__ Wwh,
                                               const float* __restrict__ wb, f16* __restrict__ wy,
                                               float* __restrict__ stats) {
  __shared__ float part[2][8][64];
  int lane = threadIdx.x & 63, wave = threadIdx.x >> 6;
  int lr = lane & 15, lg = lane >> 4;
  int wr = wave >> 1, wc = wave & 1;
  int c0 = blockIdx.y * 64 + wc * 32;
  half8 w[4][2];
  for (int k0 = 0; k0 < 4; ++k0)
    for (int j = 0; j < 2; ++j)
      w[k0][j] = *(const half8*)(Wwh + (size_t)(c0 + j * 16 + lr) * DD + k0 * 32 + lg * 8);
  float bias[2];
  for (int j = 0; j < 2; ++j) bias[j] = wb[c0 + j * 16 + lr];
  float ps[2][2] = {};
  for (int mt = 0; mt < 8; ++mt) {
    int m0 = (blockIdx.x * 8 + mt) * 64 + wr * 32;
    f32x4 acc[2][2] = {};
    for (int k0 = 0; k0 < 4; ++k0) {
      half8 a[2];
      for (int i = 0; i < 2; ++i)
        a[i] = *(const half8*)(Y + (size_t)(m0 + i * 16 + lr) * DD + k0 * 32 + lg * 8);
      for (int i = 0; i < 2; ++i)
        for (int j = 0; j < 2; ++j)
          acc[i][j] = mfma16(a[i], w[k0][j], acc[i][j]);
    }
    for (int i = 0; i < 2; ++i)
      for (int j = 0; j < 2; ++j)
        for (int r = 0; r < 4; ++r) {
          int row = m0 + i * 16 + lg * 4 + r;
          int col = c0 + j * 16 + lr;
          float v = acc[i][j][r] + bias[j];
          wy[(size_t)row * CC + col] = (f16)v;
          ps[j][0] += v;
          ps[j][1] += v * v;
        }
  }
  for (int j = 0; j < 2; ++j) {
    int colL = wc * 32 + j * 16 + lr;
    part[0][wr * 4 + lg][colL] = ps[j][0];
    part[1][wr * 4 + lg][colL] = ps[j][1];
  }
  __syncthreads();
  if (threadIdx.x < 128) {
    int metric = threadIdx.x >> 6, col = threadIdx.x & 63;
    float s = 0.f;
    for (int wtr = 0; wtr < 8; ++wtr) s += part[metric][wtr][col];
    atomicAdd(&stats[metric * CC + blockIdx.y * 64 + col], s);
  }
}

// ---------- BN apply + residual ----------
__global__ void k_bn_apply(const f16* __restrict__ wy, const float* __restrict__ x,
                           const float* __restrict__ stats, const float* __restrict__ gamma,
                           const float* __restrict__ beta, float* __restrict__ out) {
  __shared__ f16 tile[32][33];
  int b = blockIdx.z, c0 = blockIdx.y * 32, n0 = blockIdx.x * 32;
  int tx = threadIdx.x, ty = threadIdx.y;
  for (int j = 0; j < 4; ++j) {
    int nn = ty + j * 8;
    tile[nn][tx] = wy[((size_t)b * NN + n0 + nn) * CC + c0 + tx];
  }
  __syncthreads();
  const float inv_cnt = 1.f / (float)(BB * NN);
  for (int j = 0; j < 4; ++j) {
    int cc = ty + j * 8;
    int c = c0 + cc;
    float mean = stats[c] * inv_cnt;
    float var = stats[CC + c] * inv_cnt - mean * mean;
    float scale = gamma[c] * rsqrtf(var + BN_EPS);
    size_t oi = ((size_t)b * CC + c) * NN + n0 + tx;
    out[oi] = ((float)tile[tx][cc] - mean) * scale + beta[c] + x[oi];
  }
}

extern "C" void kernel_launch(void* const* d_in, const int* in_sizes, int n_in,
                              void* d_out, int out_size, void* d_ws, size_t ws_size,
                              hipStream_t stream) {
  const float* x = (const float*)d_in[0];
  const float* tw = (const float*)d_in[1];
  const float* pw = (const float*)d_in[2];
  const float* gw = (const float*)d_in[3];
  const float* ww = (const float*)d_in[4];
  const float* wb = (const float*)d_in[5];
  const float* gamma = (const float*)d_in[6];
  const float* beta = (const float*)d_in[7];
  float* out = (float*)d_out;
  char* ws = (char*)d_ws;

  f16* Wcat = (f16*)(ws + 0);                 // 192 KB
  f16* Wwh = (f16*)(ws + 196608);             // 64 KB
  float* stats = (float*)(ws + 262144);       // 2 KB
  float* ml = (float*)(ws + 524288);          // 512 KB
  const size_t BASE = 1 << 20;
  f16* T = (f16*)(ws + BASE);                 // 8 MB
  f16* P = (f16*)(ws + BASE + 8388608);       // 8 MB
  f16* Gdn = (f16*)(ws + BASE + 16777216);    // 8 MB
  f16* Yb = (f16*)(ws + BASE + 25165824);     // 8 MB (acc0; merged in place)
  f16* acc1 = (f16*)(ws + BASE + 33554432);   // 8 MB
  f16* wy = (f16*)(ws + BASE + 41943040);     // 16 MB

  k_cast_weights<<<512, 256, 0, stream>>>(tw, pw, gw, ww, Wcat, Wwh, stats);
  k_gemm1<<<dim3(NN / 64, BB), 256, 0, stream>>>(x, Wcat, T, P, Gdn);
  k_flash<<<1024, 256, 0, stream>>>(T, P, Gdn, Yb, acc1, ml);
  k_merge<<<2048, 256, 0, stream>>>(Yb, acc1, ml, Yb);
  k_gemm2<<<dim3(BB * NN / 512, CC / 64), 256, 0, stream>>>(Yb, Wwh, wb, wy, stats);
  k_bn_apply<<<dim3(NN / 32, CC / 32, BB), dim3(32, 8), 0, stream>>>(wy, x, stats, gamma, beta, out);
}